// Round 1
// baseline (177.909 us; speedup 1.0000x reference)
//
#include <hip/hip_runtime.h>
#include <hip/hip_bf16.h>

// RNN cell: out[B,N] = tanh( concat(x,hidden)[B,K] @ W^T[K,N] + b[N] )
// B(M)=16384, N=1024, K=2048 (K-halves: x then hidden), fp32 in/out.
// bf16 MFMA GEMM, fused fp32->bf16 conversion in LDS staging.

typedef __bf16 bf16_t;
typedef __bf16 bf16x8 __attribute__((ext_vector_type(8)));
typedef float  f32x4  __attribute__((ext_vector_type(4)));

#define BM 128
#define BN 128
#define BK 64
#define M_GLOBAL 16384
#define N_GLOBAL 1024
#define K_GLOBAL 2048
#define IN_STRIDE 1024   // x / hidden row stride (f32 elems)
#define W_STRIDE  2048   // W row stride (f32 elems)

__global__ __launch_bounds__(256, 2)
void rnncell_gemm(const float* __restrict__ x, const float* __restrict__ h,
                  const float* __restrict__ W, const float* __restrict__ bias,
                  float* __restrict__ out)
{
    // LDS tiles [128 rows][64 k] bf16, 128B/row. 16B slots XOR-swizzled by (row&7)
    // so ds_read_b128 of a 16-row column-slice is 2-way (free) instead of 8-way.
    __shared__ __align__(16) bf16_t As[BM * BK];
    __shared__ __align__(16) bf16_t Bs[BN * BK];

    const int tid = threadIdx.x;
    const int bid = blockIdx.x;
    // XCD-aware: bid%8 -> XCD (round-robin), so each XCD owns one N-column of
    // the grid; its 1MB W-panel stays L2-resident for the whole kernel.
    const int bm = (bid >> 3) * BM;
    const int bn = (bid & 7) * BN;

    const int lane = tid & 63;
    const int wid  = tid >> 6;
    const int wr = (wid >> 1) * 64;   // wave row offset in tile
    const int wc = (wid & 1) * 64;    // wave col offset in tile
    const int lr = lane & 15;         // frag row/col within 16
    const int lk = lane >> 4;         // k-group 0..3 (8 contiguous k each)

    f32x4 acc[4][4];
#pragma unroll
    for (int i = 0; i < 4; ++i)
#pragma unroll
        for (int j = 0; j < 4; ++j)
            acc[i][j] = (f32x4){0.f, 0.f, 0.f, 0.f};

    for (int t = 0; t < K_GLOBAL / BK; ++t) {
        const int k0 = t * BK;
        // A K-tile comes entirely from x (k0<1024) or hidden (k0>=1024)
        const float* srcA = (k0 < 1024)
            ? (x + (size_t)bm * IN_STRIDE + k0)
            : (h + (size_t)bm * IN_STRIDE + (k0 - 1024));
        const float* srcB = W + (size_t)bn * W_STRIDE + k0;

        // ---- stage: 128x64 f32 per operand; unit = 8 f32 (=> one bf16x8 slot)
        // 1024 units/operand, 4 per thread. Consecutive lanes -> consecutive
        // 32B chunks (two float4 loads 16B apart), coalesced within-pair.
        float4 la[4][2], lb[4][2];
#pragma unroll
        for (int i = 0; i < 4; ++i) {
            const int u   = tid + i * 256;
            const int row = u >> 3;
            const int sl  = u & 7;
            const float* pa = srcA + (size_t)row * IN_STRIDE + sl * 8;
            la[i][0] = *(const float4*)(pa);
            la[i][1] = *(const float4*)(pa + 4);
            const float* pb = srcB + (size_t)row * W_STRIDE + sl * 8;
            lb[i][0] = *(const float4*)(pb);
            lb[i][1] = *(const float4*)(pb + 4);
        }

        __syncthreads();   // previous iteration's ds_reads complete

#pragma unroll
        for (int i = 0; i < 4; ++i) {
            const int u   = tid + i * 256;
            const int row = u >> 3;
            const int sl  = u & 7;
            const int ssl = sl ^ (row & 7);
            bf16x8 va, vb;
            va[0] = (bf16_t)la[i][0].x; va[1] = (bf16_t)la[i][0].y;
            va[2] = (bf16_t)la[i][0].z; va[3] = (bf16_t)la[i][0].w;
            va[4] = (bf16_t)la[i][1].x; va[5] = (bf16_t)la[i][1].y;
            va[6] = (bf16_t)la[i][1].z; va[7] = (bf16_t)la[i][1].w;
            vb[0] = (bf16_t)lb[i][0].x; vb[1] = (bf16_t)lb[i][0].y;
            vb[2] = (bf16_t)lb[i][0].z; vb[3] = (bf16_t)lb[i][0].w;
            vb[4] = (bf16_t)lb[i][1].x; vb[5] = (bf16_t)lb[i][1].y;
            vb[6] = (bf16_t)lb[i][1].z; vb[7] = (bf16_t)lb[i][1].w;
            *(bf16x8*)(As + row * BK + ssl * 8) = va;
            *(bf16x8*)(Bs + row * BK + ssl * 8) = vb;
        }

        __syncthreads();   // tile visible

        // ---- compute: 2 k-halves x 4x4 frags of 16x16x32
#pragma unroll
        for (int kk = 0; kk < 2; ++kk) {
            bf16x8 af[4], bfr[4];
#pragma unroll
            for (int mf = 0; mf < 4; ++mf) {
                const int row = wr + mf * 16 + lr;
                const int sl  = (kk * 4 + lk) ^ (row & 7);
                af[mf] = *(const bf16x8*)(As + row * BK + sl * 8);
            }
#pragma unroll
            for (int nf = 0; nf < 4; ++nf) {
                const int row = wc + nf * 16 + lr;
                const int sl  = (kk * 4 + lk) ^ (row & 7);
                bfr[nf] = *(const bf16x8*)(Bs + row * BK + sl * 8);
            }
#pragma unroll
            for (int mf = 0; mf < 4; ++mf)
#pragma unroll
                for (int nf = 0; nf < 4; ++nf)
                    acc[mf][nf] = __builtin_amdgcn_mfma_f32_16x16x32_bf16(
                        af[mf], bfr[nf], acc[mf][nf], 0, 0, 0);
        }
    }

    // ---- epilogue: bias + tanh, fp32 store
    // C/D layout (verified m89/m91): col = lane&15, row = (lane>>4)*4 + reg
    float bv[4];
#pragma unroll
    for (int nf = 0; nf < 4; ++nf)
        bv[nf] = bias[bn + wc + nf * 16 + lr];
#pragma unroll
    for (int mf = 0; mf < 4; ++mf) {
#pragma unroll
        for (int nf = 0; nf < 4; ++nf) {
            const int col = bn + wc + nf * 16 + lr;
#pragma unroll
            for (int r = 0; r < 4; ++r) {
                const int row = bm + wr + mf * 16 + lk * 4 + r;
                out[(size_t)row * N_GLOBAL + col] = tanhf(acc[mf][nf][r] + bv[nf]);
            }
        }
    }
}

extern "C" void kernel_launch(void* const* d_in, const int* in_sizes, int n_in,
                              void* d_out, int out_size, void* d_ws, size_t ws_size,
                              hipStream_t stream) {
    (void)in_sizes; (void)n_in; (void)d_ws; (void)ws_size; (void)out_size;
    const float* x = (const float*)d_in[0];
    const float* h = (const float*)d_in[1];
    const float* W = (const float*)d_in[2];
    const float* b = (const float*)d_in[3];
    float* out = (float*)d_out;
    dim3 grid((M_GLOBAL / BM) * (N_GLOBAL / BN));  // 128 * 8 = 1024
    rnncell_gemm<<<grid, 256, 0, stream>>>(x, h, W, b, out);
}